// Round 9
// baseline (778.681 us; speedup 1.0000x reference)
//
#include <hip/hip_runtime.h>

#define B_ 16
#define N_ 8192
#define D_ 512
#define M_ 1024
#define BT 64
#define SCALE 0.04419417382415922f  // 1/sqrt(512)

typedef __attribute__((ext_vector_type(8))) short short8;
typedef __attribute__((ext_vector_type(4))) short short4v;
typedef __attribute__((ext_vector_type(4))) float f32x4;
typedef __attribute__((ext_vector_type(16))) float f32x16;

__device__ __forceinline__ unsigned short f2bf(float f) {
  unsigned int u = __float_as_uint(f);
  u += 0x7FFFu + ((u >> 16) & 1u);  // RNE
  return (unsigned short)(u >> 16);
}
__device__ __forceinline__ float bf2f(unsigned short h) {
  return __uint_as_float(((unsigned int)h) << 16);
}

#define MFMA32(a, b, c) __builtin_amdgcn_mfma_f32_32x32x16_bf16((a), (b), (c), 0, 0, 0)

// Fragment-block layouts (1KB contiguous per (tile,kstep), 64 lanes x 16B):
// memTbF: GEMM1 A (scaled mem, rows=m): block (MT 0..31, kk 0..31):
//   elem[l][j] = SCALE*mem[ (kk*16 + (l>>5)*8 + j) ][ MT*32 + (l&31) ]
// memDF:  GEMM2 B (mem, cols=d): block (DT 0..15, kg 0..63):
//   elem[l][j] = mem[ DT*32 + (l&31) ][ kg*16 + (l>>5)*8 + j ]
__global__ void prep_mem_kernel(const float* __restrict__ mem,
                                unsigned short* __restrict__ memTbF,
                                unsigned short* __restrict__ memDF) {
  int t = blockIdx.x * 256 + threadIdx.x;  // 0 .. D*M-1
  int j = t & 7, l = (t >> 3) & 63, blk = t >> 9;
  {
    int kk = blk & 31, MT = blk >> 5;
    int m = MT * 32 + (l & 31);
    int d = kk * 16 + ((l >> 5) << 3) + j;
    memTbF[t] = f2bf(mem[d * M_ + m] * SCALE);
  }
  {
    int kg = blk & 63, DT = blk >> 6;
    int d = DT * 32 + (l & 31);
    int m = kg * 16 + ((l >> 5) << 3) + j;
    memDF[t] = f2bf(mem[d * M_ + m]);
  }
}

__global__ __launch_bounds__(256, 2) void fused_kernel(
    const float* __restrict__ x, const unsigned short* __restrict__ memTbF,
    const unsigned short* __restrict__ memDF, float* __restrict__ out) {
  __shared__ unsigned short sX[32768];  // 64 KB: X bf16, 64 rows x 1024B, XOR-swizzled
  __shared__ unsigned short sPa[8192];  // 16 KB: P bf16, 64 rows x 256B, XOR-swizzled
  float* psums = (float*)sX;            // [4][64], alias (sX dead by then)
  float* sInv = ((float*)sX) + 256;     // [64]

  const int tid = threadIdx.x;
  const int w = tid >> 6;     // wave 0..3
  const int lane = tid & 63;
  const int c31 = lane & 31;
  const int l5 = lane >> 5;
  const int e7 = lane & 7;
  const int t15 = c31 & 15;
  const long t0 = (long)blockIdx.x * BT;

  // ---- Stage X -> bf16 -> swizzled sX (slot' = slot ^ (row&7), 16B slots) ----
  {
    const int row = tid >> 2, cg = tid & 3;
    const int r7 = row & 7;
    const float* xp = x + (t0 + row) * (long)D_ + cg * 128;
    char* sxb = (char*)sX + (row << 10);
#pragma unroll
    for (int j = 0; j < 16; j++) {
      f32x4 v0 = *(const f32x4*)(xp + j * 8);
      f32x4 v1 = *(const f32x4*)(xp + j * 8 + 4);
      short8 o;
      o[0] = (short)f2bf(v0[0]);
      o[1] = (short)f2bf(v0[1]);
      o[2] = (short)f2bf(v0[2]);
      o[3] = (short)f2bf(v0[3]);
      o[4] = (short)f2bf(v1[0]);
      o[5] = (short)f2bf(v1[1]);
      o[6] = (short)f2bf(v1[2]);
      o[7] = (short)f2bf(v1[3]);
      int s = (cg << 4) + j;  // 16B-slot within the 1024B row
      *(short8*)(sxb + ((s ^ r7) << 4)) = o;
    }
  }
  __syncthreads();

  f32x16 oacc[2][4];  // [tok-tile][d-tile]; C: col d=w*128+d0*32+(l&31), row tok
#pragma unroll
  for (int tt = 0; tt < 2; tt++)
#pragma unroll
    for (int d0 = 0; d0 < 4; d0++) oacc[tt][d0] = (f32x16)0.0f;
  f32x16 sacc[2];     // S chunk: col tok = tt*32+(l&31), row m_local of wave's 32-m slice
  float fsum[2] = {0.f, 0.f};

  char* const bx0 = (char*)sX + (c31 << 10);
  char* const bx1 = (char*)sX + ((32 + c31) << 10);
  char* const bp0 = (char*)sPa + (c31 << 8);
  char* const bp1 = (char*)sPa + ((32 + c31) << 8);

  // Cross-barrier register prefetch: next region's leading global fragments.
  // __syncthreads() drains vmcnt(0) anyway, so loads issued in the previous
  // region complete into VGPRs "for free" and the next region starts hot.
  short8 pf_gb[8];  // GEMM2 chunk cg2: d-tiles 0..3 x k0 0..1
  short8 pf_ga[8];  // GEMM1 chunk cg1: kk 0..7
  auto issue_pf = [&](int cg2, int cg1) {
    const short8* gb =
        (const short8*)memDF + ((size_t)(w * 4) * 64 + cg2 * 8) * 64 + lane;
#pragma unroll
    for (int t = 0; t < 4; t++) {
      pf_gb[t * 2] = gb[(t * 64) * 64];
      pf_gb[t * 2 + 1] = gb[(t * 64 + 1) * 64];
    }
    if (cg1 < 8) {
      const short8* ga =
          (const short8*)memTbF + (size_t)((cg1 * 4 + w) * 32) * 64 + lane;
#pragma unroll
      for (int kk = 0; kk < 8; kk++) pf_ga[kk] = ga[kk * 64];
    }
  };

  // GEMM1 for chunk ch (m-tile MT = ch*4+w): S = memTbF_tile * X
  auto gemm1 = [&](int ch) {
    sacc[0] = (f32x16)0.0f;
    sacc[1] = (f32x16)0.0f;
    const short8* ga = (const short8*)memTbF + (size_t)((ch * 4 + w) * 32) * 64 + lane;
#pragma unroll
    for (int kk = 0; kk < 32; kk++) {
      short8 a = ga[kk * 64];
      int sw = (((kk << 1) | l5) ^ e7) << 4;
      short8 x0 = *(const short8*)(bx0 + sw);
      short8 x1 = *(const short8*)(bx1 + sw);
      sacc[0] = MFMA32(a, x0, sacc[0]);
      sacc[1] = MFMA32(a, x1, sacc[1]);
    }
  };

  // P = exp(S) -> bf16 -> swizzled sPa (rows=tok, 256B; slot' = slot ^ (tok&15))
  auto pgen = [&]() {
#pragma unroll
    for (int tt = 0; tt < 2; tt++) {
      int tok = tt * 32 + c31;
      char* base = (char*)sPa + (tok << 8);
      float s = 0.f;
      unsigned short pb[16];
#pragma unroll
      for (int q = 0; q < 16; q++) {
        float p = __expf(sacc[tt][q]);
        unsigned short b = f2bf(p);
        pb[q] = b;
        s += bf2f(b);  // sum the rounded values GEMM2 will use
      }
      fsum[tt] += s;
#pragma unroll
      for (int q = 0; q < 4; q++) {
        short4v o = {(short)pb[q * 4], (short)pb[q * 4 + 1],
                     (short)pb[q * 4 + 2], (short)pb[q * 4 + 3]};
        int sl = ((w << 2) | q) ^ t15;
        *(short4v*)(base + (sl << 4) + (l5 << 3)) = o;
      }
    }
  };

  gemm1(0);
  pgen();
  issue_pf(0, 1);

#pragma unroll 1
  for (int c = 0; c < 8; c++) {
    __syncthreads();  // bar A: sPa(c) ready (also completes prefetched loads)
    if (c == 7 && tid < BT) {
      float s = psums[tid] + psums[64 + tid] + psums[128 + tid] + psums[192 + tid];
      sInv[tid] = 1.0f / s;
    }
    // ---- region: GEMM2(c) interleaved with GEMM1(c+1) ----
    {
      const short8* gb = (const short8*)memDF + ((size_t)(w * 4) * 64 + c * 8) * 64 + lane;
      const bool doG1 = (c < 7);
      const short8* ga = (const short8*)memTbF +
                         (size_t)((((c + 1) & 7) * 4 + w) * 32) * 64 + lane;
      if (doG1) {
        sacc[0] = (f32x16)0.0f;
        sacc[1] = (f32x16)0.0f;
      }
#pragma unroll
      for (int k0 = 0; k0 < 8; k0++) {
        int sp = ((((k0 << 1) | l5) ^ t15) << 4);
        short8 p0 = *(const short8*)(bp0 + sp);
        short8 p1 = *(const short8*)(bp1 + sp);
        short8 b0 = (k0 < 2) ? pf_gb[0 * 2 + k0] : gb[(0 * 64 + k0) * 64];
        short8 b1 = (k0 < 2) ? pf_gb[1 * 2 + k0] : gb[(1 * 64 + k0) * 64];
        short8 b2 = (k0 < 2) ? pf_gb[2 * 2 + k0] : gb[(2 * 64 + k0) * 64];
        short8 b3 = (k0 < 2) ? pf_gb[3 * 2 + k0] : gb[(3 * 64 + k0) * 64];
        oacc[0][0] = MFMA32(p0, b0, oacc[0][0]);
        oacc[1][0] = MFMA32(p1, b0, oacc[1][0]);
        oacc[0][1] = MFMA32(p0, b1, oacc[0][1]);
        oacc[1][1] = MFMA32(p1, b1, oacc[1][1]);
        oacc[0][2] = MFMA32(p0, b2, oacc[0][2]);
        oacc[1][2] = MFMA32(p1, b2, oacc[1][2]);
        oacc[0][3] = MFMA32(p0, b3, oacc[0][3]);
        oacc[1][3] = MFMA32(p1, b3, oacc[1][3]);
        if (doG1) {
#pragma unroll
          for (int kq = 0; kq < 4; kq++) {
            int kk = k0 * 4 + kq;
            short8 a = (kk < 8) ? pf_ga[kk] : ga[kk * 64];
            int sw = (((kk << 1) | l5) ^ e7) << 4;
            short8 x0 = *(const short8*)(bx0 + sw);
            short8 x1 = *(const short8*)(bx1 + sw);
            sacc[0] = MFMA32(a, x0, sacc[0]);
            sacc[1] = MFMA32(a, x1, sacc[1]);
          }
        }
      }
    }
    __syncthreads();  // bar B: sPa(c) consumed by all waves
    if (c < 7) {
      issue_pf(c + 1, c + 2);  // loads fly during pgen + barA of next iter
      pgen();
      if (c == 6) {  // fsum now complete; publish per-wave partials (into dead sX)
        float s0 = fsum[0] + __shfl_xor(fsum[0], 32);
        float s1 = fsum[1] + __shfl_xor(fsum[1], 32);
        if (lane < 32) {
          psums[w * 64 + lane] = s0;
          psums[w * 64 + 32 + lane] = s1;
        }
      }
    }
  }

  // ---- Epilogue: O * (1/sum) ----
#pragma unroll
  for (int tt = 0; tt < 2; tt++) {
#pragma unroll
    for (int q = 0; q < 16; q++) {
      int tok = tt * 32 + (q & 3) + ((q >> 2) << 3) + (l5 << 2);
      float inv = sInv[tok];
      float* op = out + (t0 + tok) * (long)D_ + w * 128 + c31;
#pragma unroll
      for (int d0 = 0; d0 < 4; d0++) op[d0 * 32] = oacc[tt][d0][q] * inv;
    }
  }
}

extern "C" void kernel_launch(void* const* d_in, const int* in_sizes, int n_in,
                              void* d_out, int out_size, void* d_ws, size_t ws_size,
                              hipStream_t stream) {
  const float* x = (const float*)d_in[0];
  const float* mem = (const float*)d_in[1];
  float* out = (float*)d_out;
  unsigned short* memTbF = (unsigned short*)d_ws;    // 1 MB frag-layout (scaled)
  unsigned short* memDF = memTbF + (size_t)D_ * M_;  // 1 MB frag-layout

  hipLaunchKernelGGL(prep_mem_kernel, dim3((D_ * M_) / 256), dim3(256), 0, stream,
                     mem, memTbF, memDF);
  hipLaunchKernelGGL(fused_kernel, dim3((B_ * N_) / BT), dim3(256), 0, stream,
                     x, memTbF, memDF, out);
}

// Round 10
// 711.997 us; speedup vs baseline: 1.0937x; 1.0937x over previous
//
#include <hip/hip_runtime.h>

#define B_ 16
#define N_ 8192
#define D_ 512
#define M_ 1024
#define BT 64
#define SCALE 0.04419417382415922f  // 1/sqrt(512)

typedef __attribute__((ext_vector_type(8))) short short8;
typedef __attribute__((ext_vector_type(4))) short short4v;
typedef __attribute__((ext_vector_type(4))) float f32x4;
typedef __attribute__((ext_vector_type(16))) float f32x16;

__device__ __forceinline__ unsigned short f2bf(float f) {
  unsigned int u = __float_as_uint(f);
  u += 0x7FFFu + ((u >> 16) & 1u);  // RNE
  return (unsigned short)(u >> 16);
}
__device__ __forceinline__ float bf2f(unsigned short h) {
  return __uint_as_float(((unsigned int)h) << 16);
}

#define MFMA32(a, b, c) __builtin_amdgcn_mfma_f32_32x32x16_bf16((a), (b), (c), 0, 0, 0)

// Fragment-block layouts (1KB contiguous per (tile,kstep), 64 lanes x 16B):
// memTbF: GEMM1 A (scaled mem, rows=m): block (MT 0..31, kk 0..31):
//   elem[l][j] = SCALE*mem[ (kk*16 + (l>>5)*8 + j) ][ MT*32 + (l&31) ]
// memDF:  GEMM2 B (mem, cols=d): block (DT 0..15, kg 0..63):
//   elem[l][j] = mem[ DT*32 + (l&31) ][ kg*16 + (l>>5)*8 + j ]
__global__ void prep_mem_kernel(const float* __restrict__ mem,
                                unsigned short* __restrict__ memTbF,
                                unsigned short* __restrict__ memDF) {
  int t = blockIdx.x * 256 + threadIdx.x;  // 0 .. D*M-1
  int j = t & 7, l = (t >> 3) & 63, blk = t >> 9;
  {
    int kk = blk & 31, MT = blk >> 5;
    int m = MT * 32 + (l & 31);
    int d = kk * 16 + ((l >> 5) << 3) + j;
    memTbF[t] = f2bf(mem[d * M_ + m] * SCALE);
  }
  {
    int kg = blk & 63, DT = blk >> 6;
    int d = DT * 32 + (l & 31);
    int m = kg * 16 + ((l >> 5) << 3) + j;
    memDF[t] = f2bf(mem[d * M_ + m]);
  }
}

__global__ __launch_bounds__(256, 2) void fused_kernel(
    const float* __restrict__ x, const unsigned short* __restrict__ memTbF,
    const unsigned short* __restrict__ memDF, float* __restrict__ out) {
  __shared__ unsigned short sX[32768];  // 64 KB: X bf16, 64 rows x 1024B, XOR-swizzled
  __shared__ unsigned short sPa[8192];  // 16 KB: P bf16, 64 rows x 256B, XOR-swizzled
  float* psums = (float*)sX;            // [4][64], alias (sX dead by then)
  float* sInv = ((float*)sX) + 256;     // [64]

  const int tid = threadIdx.x;
  const int w = tid >> 6;     // wave 0..3
  const int lane = tid & 63;
  const int c31 = lane & 31;
  const int l5 = lane >> 5;
  const int e7 = lane & 7;
  const int t15 = c31 & 15;
  const long t0 = (long)blockIdx.x * BT;

  // ---- Stage X -> bf16 -> swizzled sX (slot' = slot ^ (row&7), 16B slots) ----
  {
    const int row = tid >> 2, cg = tid & 3;
    const int r7 = row & 7;
    const float* xp = x + (t0 + row) * (long)D_ + cg * 128;
    char* sxb = (char*)sX + (row << 10);
#pragma unroll
    for (int j = 0; j < 16; j++) {
      f32x4 v0 = *(const f32x4*)(xp + j * 8);
      f32x4 v1 = *(const f32x4*)(xp + j * 8 + 4);
      short8 o;
      o[0] = (short)f2bf(v0[0]);
      o[1] = (short)f2bf(v0[1]);
      o[2] = (short)f2bf(v0[2]);
      o[3] = (short)f2bf(v0[3]);
      o[4] = (short)f2bf(v1[0]);
      o[5] = (short)f2bf(v1[1]);
      o[6] = (short)f2bf(v1[2]);
      o[7] = (short)f2bf(v1[3]);
      int s = (cg << 4) + j;  // 16B-slot within the 1024B row
      *(short8*)(sxb + ((s ^ r7) << 4)) = o;
    }
  }
  __syncthreads();

  f32x16 oacc[2][4];  // [tok-tile][d-tile]; C: col d=w*128+d0*32+(l&31), row tok
#pragma unroll
  for (int tt = 0; tt < 2; tt++)
#pragma unroll
    for (int d0 = 0; d0 < 4; d0++) oacc[tt][d0] = (f32x16)0.0f;
  f32x16 sacc[2];     // S chunk: col tok = tt*32+(l&31), row m_local of wave's 32-m slice
  float fsum[2] = {0.f, 0.f};

  char* const bx0 = (char*)sX + (c31 << 10);
  char* const bx1 = (char*)sX + ((32 + c31) << 10);
  char* const bp0 = (char*)sPa + (c31 << 8);
  char* const bp1 = (char*)sPa + ((32 + c31) << 8);

  // Cross-barrier prefetch: NAMED registers only (arrays spilled to scratch in
  // a previous attempt). Loads are issued right after barB, fly during pgen,
  // and complete at barA's implicit vmcnt(0) drain -> region starts hot.
  short8 pb0, pb1, pb2, pb3;  // GEMM2 chunk head, k0=0, d-tiles 0..3
  short8 qb0, qb1, qb2, qb3;  // GEMM2 chunk head, k0=1
  short8 pa0, pa1, pa2, pa3;  // GEMM1 chunk head, kk=0..3

  auto issue_pf = [&](int c2, int c1) {
    const short8* gb =
        (const short8*)memDF + ((size_t)(w * 4) * 64 + c2 * 8) * 64 + lane;
    pb0 = gb[(0 * 64 + 0) * 64];
    qb0 = gb[(0 * 64 + 1) * 64];
    pb1 = gb[(1 * 64 + 0) * 64];
    qb1 = gb[(1 * 64 + 1) * 64];
    pb2 = gb[(2 * 64 + 0) * 64];
    qb2 = gb[(2 * 64 + 1) * 64];
    pb3 = gb[(3 * 64 + 0) * 64];
    qb3 = gb[(3 * 64 + 1) * 64];
    const short8* ga =
        (const short8*)memTbF + (size_t)((c1 * 4 + w) * 32) * 64 + lane;
    pa0 = ga[0 * 64];
    pa1 = ga[1 * 64];
    pa2 = ga[2 * 64];
    pa3 = ga[3 * 64];
  };

  // GEMM1 for chunk ch (m-tile MT = ch*4+w): S = memTbF_tile * X
  auto gemm1 = [&](int ch) {
    sacc[0] = (f32x16)0.0f;
    sacc[1] = (f32x16)0.0f;
    const short8* ga = (const short8*)memTbF + (size_t)((ch * 4 + w) * 32) * 64 + lane;
#pragma unroll
    for (int kk = 0; kk < 32; kk++) {
      short8 a = ga[kk * 64];
      int sw = (((kk << 1) | l5) ^ e7) << 4;
      short8 x0 = *(const short8*)(bx0 + sw);
      short8 x1 = *(const short8*)(bx1 + sw);
      sacc[0] = MFMA32(a, x0, sacc[0]);
      sacc[1] = MFMA32(a, x1, sacc[1]);
    }
  };

  // P = exp(S) -> bf16 -> swizzled sPa (rows=tok, 256B; slot' = slot ^ (tok&15))
  auto pgen = [&]() {
#pragma unroll
    for (int tt = 0; tt < 2; tt++) {
      int tok = tt * 32 + c31;
      char* base = (char*)sPa + (tok << 8);
      float s = 0.f;
      unsigned short pb[16];
#pragma unroll
      for (int q = 0; q < 16; q++) {
        float p = __expf(sacc[tt][q]);
        unsigned short b = f2bf(p);
        pb[q] = b;
        s += bf2f(b);  // sum the rounded values GEMM2 will use
      }
      fsum[tt] += s;
#pragma unroll
      for (int q = 0; q < 4; q++) {
        short4v o = {(short)pb[q * 4], (short)pb[q * 4 + 1],
                     (short)pb[q * 4 + 2], (short)pb[q * 4 + 3]};
        int sl = ((w << 2) | q) ^ t15;
        *(short4v*)(base + (sl << 4) + (l5 << 3)) = o;
      }
    }
  };

  gemm1(0);
  issue_pf(0, 1);
  pgen();

#pragma unroll 1
  for (int c = 0; c < 8; c++) {
    __syncthreads();  // bar A: sPa(c) ready (also completes prefetched loads)
    if (c == 7 && tid < BT) {
      float s = psums[tid] + psums[64 + tid] + psums[128 + tid] + psums[192 + tid];
      sInv[tid] = 1.0f / s;
    }
    // ---- region: GEMM2(c) interleaved with GEMM1(c+1) ----
    {
      const short8* gb = (const short8*)memDF + ((size_t)(w * 4) * 64 + c * 8) * 64 + lane;
      const bool doG1 = (c < 7);
      const short8* ga = (const short8*)memTbF +
                         (size_t)((((c + 1) & 7) * 4 + w) * 32) * 64 + lane;
      if (doG1) {
        sacc[0] = (f32x16)0.0f;
        sacc[1] = (f32x16)0.0f;
      }
      // ---- k0 = 0 (peeled; uses prefetched pb*, pa0..pa3) ----
      {
        int sp = ((l5 ^ t15) << 4);
        short8 p0 = *(const short8*)(bp0 + sp);
        short8 p1 = *(const short8*)(bp1 + sp);
        oacc[0][0] = MFMA32(p0, pb0, oacc[0][0]);
        oacc[1][0] = MFMA32(p1, pb0, oacc[1][0]);
        oacc[0][1] = MFMA32(p0, pb1, oacc[0][1]);
        oacc[1][1] = MFMA32(p1, pb1, oacc[1][1]);
        oacc[0][2] = MFMA32(p0, pb2, oacc[0][2]);
        oacc[1][2] = MFMA32(p1, pb2, oacc[1][2]);
        oacc[0][3] = MFMA32(p0, pb3, oacc[0][3]);
        oacc[1][3] = MFMA32(p1, pb3, oacc[1][3]);
        if (doG1) {
          int sw0 = ((0 | l5) ^ e7) << 4;
          int sw1 = ((2 | l5) ^ e7) << 4;
          int sw2 = ((4 | l5) ^ e7) << 4;
          int sw3 = ((6 | l5) ^ e7) << 4;
          sacc[0] = MFMA32(pa0, *(const short8*)(bx0 + sw0), sacc[0]);
          sacc[1] = MFMA32(pa0, *(const short8*)(bx1 + sw0), sacc[1]);
          sacc[0] = MFMA32(pa1, *(const short8*)(bx0 + sw1), sacc[0]);
          sacc[1] = MFMA32(pa1, *(const short8*)(bx1 + sw1), sacc[1]);
          sacc[0] = MFMA32(pa2, *(const short8*)(bx0 + sw2), sacc[0]);
          sacc[1] = MFMA32(pa2, *(const short8*)(bx1 + sw2), sacc[1]);
          sacc[0] = MFMA32(pa3, *(const short8*)(bx0 + sw3), sacc[0]);
          sacc[1] = MFMA32(pa3, *(const short8*)(bx1 + sw3), sacc[1]);
        }
      }
      // ---- k0 = 1 (peeled; uses prefetched qb*) ----
      {
        int sp = (((2 | l5) ^ t15) << 4);
        short8 p0 = *(const short8*)(bp0 + sp);
        short8 p1 = *(const short8*)(bp1 + sp);
        oacc[0][0] = MFMA32(p0, qb0, oacc[0][0]);
        oacc[1][0] = MFMA32(p1, qb0, oacc[1][0]);
        oacc[0][1] = MFMA32(p0, qb1, oacc[0][1]);
        oacc[1][1] = MFMA32(p1, qb1, oacc[1][1]);
        oacc[0][2] = MFMA32(p0, qb2, oacc[0][2]);
        oacc[1][2] = MFMA32(p1, qb2, oacc[1][2]);
        oacc[0][3] = MFMA32(p0, qb3, oacc[0][3]);
        oacc[1][3] = MFMA32(p1, qb3, oacc[1][3]);
        if (doG1) {
#pragma unroll
          for (int kq = 4; kq < 8; kq++) {
            short8 a = ga[kq * 64];
            int sw = (((kq << 1) | l5) ^ e7) << 4;
            short8 x0 = *(const short8*)(bx0 + sw);
            short8 x1 = *(const short8*)(bx1 + sw);
            sacc[0] = MFMA32(a, x0, sacc[0]);
            sacc[1] = MFMA32(a, x1, sacc[1]);
          }
        }
      }
      // ---- k0 = 2..7 ----
#pragma unroll
      for (int k0 = 2; k0 < 8; k0++) {
        int sp = ((((k0 << 1) | l5) ^ t15) << 4);
        short8 p0 = *(const short8*)(bp0 + sp);
        short8 p1 = *(const short8*)(bp1 + sp);
        short8 b0 = gb[(0 * 64 + k0) * 64];
        short8 b1 = gb[(1 * 64 + k0) * 64];
        short8 b2 = gb[(2 * 64 + k0) * 64];
        short8 b3 = gb[(3 * 64 + k0) * 64];
        oacc[0][0] = MFMA32(p0, b0, oacc[0][0]);
        oacc[1][0] = MFMA32(p1, b0, oacc[1][0]);
        oacc[0][1] = MFMA32(p0, b1, oacc[0][1]);
        oacc[1][1] = MFMA32(p1, b1, oacc[1][1]);
        oacc[0][2] = MFMA32(p0, b2, oacc[0][2]);
        oacc[1][2] = MFMA32(p1, b2, oacc[1][2]);
        oacc[0][3] = MFMA32(p0, b3, oacc[0][3]);
        oacc[1][3] = MFMA32(p1, b3, oacc[1][3]);
        if (doG1) {
#pragma unroll
          for (int kq = 0; kq < 4; kq++) {
            int kk = k0 * 4 + kq;
            short8 a = ga[kk * 64];
            int sw = (((kk << 1) | l5) ^ e7) << 4;
            short8 x0 = *(const short8*)(bx0 + sw);
            short8 x1 = *(const short8*)(bx1 + sw);
            sacc[0] = MFMA32(a, x0, sacc[0]);
            sacc[1] = MFMA32(a, x1, sacc[1]);
          }
        }
      }
    }
    __syncthreads();  // bar B: sPa(c) consumed by all waves
    if (c < 7) {
      issue_pf(c + 1, (c + 2) & 7);  // loads fly during pgen + barA of next iter
      pgen();
      if (c == 6) {  // fsum now complete; publish per-wave partials (into dead sX)
        float s0 = fsum[0] + __shfl_xor(fsum[0], 32);
        float s1 = fsum[1] + __shfl_xor(fsum[1], 32);
        if (lane < 32) {
          psums[w * 64 + lane] = s0;
          psums[w * 64 + 32 + lane] = s1;
        }
      }
    }
  }

  // ---- Epilogue: O * (1/sum) ----
#pragma unroll
  for (int tt = 0; tt < 2; tt++) {
#pragma unroll
    for (int q = 0; q < 16; q++) {
      int tok = tt * 32 + (q & 3) + ((q >> 2) << 3) + (l5 << 2);
      float inv = sInv[tok];
      float* op = out + (t0 + tok) * (long)D_ + w * 128 + c31;
#pragma unroll
      for (int d0 = 0; d0 < 4; d0++) op[d0 * 32] = oacc[tt][d0][q] * inv;
    }
  }
}

extern "C" void kernel_launch(void* const* d_in, const int* in_sizes, int n_in,
                              void* d_out, int out_size, void* d_ws, size_t ws_size,
                              hipStream_t stream) {
  const float* x = (const float*)d_in[0];
  const float* mem = (const float*)d_in[1];
  float* out = (float*)d_out;
  unsigned short* memTbF = (unsigned short*)d_ws;    // 1 MB frag-layout (scaled)
  unsigned short* memDF = memTbF + (size_t)D_ * M_;  // 1 MB frag-layout

  hipLaunchKernelGGL(prep_mem_kernel, dim3((D_ * M_) / 256), dim3(256), 0, stream,
                     mem, memTbF, memDF);
  hipLaunchKernelGGL(fused_kernel, dim3((B_ * N_) / BT), dim3(256), 0, stream,
                     x, memTbF, memDF, out);
}

// Round 11
// 544.354 us; speedup vs baseline: 1.4305x; 1.3080x over previous
//
#include <hip/hip_runtime.h>

#define B_ 16
#define N_ 8192
#define D_ 512
#define M_ 1024
#define BT 32
#define SCALE 0.04419417382415922f  // 1/sqrt(512)

typedef __attribute__((ext_vector_type(8))) short short8;
typedef __attribute__((ext_vector_type(4))) short short4v;
typedef __attribute__((ext_vector_type(4))) float f32x4;
typedef __attribute__((ext_vector_type(16))) float f32x16;

__device__ __forceinline__ unsigned short f2bf(float f) {
  unsigned int u = __float_as_uint(f);
  u += 0x7FFFu + ((u >> 16) & 1u);  // RNE
  return (unsigned short)(u >> 16);
}
__device__ __forceinline__ float bf2f(unsigned short h) {
  return __uint_as_float(((unsigned int)h) << 16);
}

#define MFMA32(a, b, c) __builtin_amdgcn_mfma_f32_32x32x16_bf16((a), (b), (c), 0, 0, 0)

// Fragment-block layouts (1KB contiguous per (tile,kstep), 64 lanes x 16B):
// memTbF: GEMM1 A (scaled mem, rows=m): block (MT 0..31, kk 0..31):
//   elem[l][j] = SCALE*mem[ (kk*16 + (l>>5)*8 + j) ][ MT*32 + (l&31) ]
// memDF:  GEMM2 B (mem, cols=d): block (DT 0..15, kg 0..63):
//   elem[l][j] = mem[ DT*32 + (l&31) ][ kg*16 + (l>>5)*8 + j ]
__global__ void prep_mem_kernel(const float* __restrict__ mem,
                                unsigned short* __restrict__ memTbF,
                                unsigned short* __restrict__ memDF) {
  int t = blockIdx.x * 256 + threadIdx.x;  // 0 .. D*M-1
  int j = t & 7, l = (t >> 3) & 63, blk = t >> 9;
  {
    int kk = blk & 31, MT = blk >> 5;
    int m = MT * 32 + (l & 31);
    int d = kk * 16 + ((l >> 5) << 3) + j;
    memTbF[t] = f2bf(mem[d * M_ + m] * SCALE);
  }
  {
    int kg = blk & 63, DT = blk >> 6;
    int d = DT * 32 + (l & 31);
    int m = kg * 16 + ((l >> 5) << 3) + j;
    memDF[t] = f2bf(mem[d * M_ + m]);
  }
}

__global__ __launch_bounds__(256, 3) void fused_kernel(
    const float* __restrict__ x, const unsigned short* __restrict__ memTbF,
    const unsigned short* __restrict__ memDF, float* __restrict__ out) {
  __shared__ unsigned short sX[16384];  // 32 KB: X bf16, 32 rows x 1024B, XOR-swizzled
  __shared__ unsigned short sPa[4096];  // 8 KB: P bf16, 32 rows x 256B, XOR-swizzled
  float* psums = (float*)sX;            // [4][32], alias (sX dead by then)
  float* sInv = ((float*)sX) + 128;     // [32]

  const int tid = threadIdx.x;
  const int w = tid >> 6;     // wave 0..3
  const int lane = tid & 63;
  const int c31 = lane & 31;
  const int l5 = lane >> 5;
  const int e7 = lane & 7;
  const int t15 = c31 & 15;
  const long t0 = (long)blockIdx.x * BT;

  // ---- Stage X -> bf16 -> swizzled sX (slot' = slot ^ (row&7), 16B slots) ----
  {
    const int row = tid >> 3;       // 0..31
    const int cslot = tid & 7;
    const int r7 = row & 7;
    const float* xp = x + (t0 + row) * (long)D_;
    char* sxb = (char*)sX + (row << 10);
#pragma unroll
    for (int j = 0; j < 8; j++) {
      const int s = cslot + 8 * j;  // 16B-slot 0..63 within the row
      f32x4 v0 = *(const f32x4*)(xp + s * 8);
      f32x4 v1 = *(const f32x4*)(xp + s * 8 + 4);
      short8 o;
      o[0] = (short)f2bf(v0[0]);
      o[1] = (short)f2bf(v0[1]);
      o[2] = (short)f2bf(v0[2]);
      o[3] = (short)f2bf(v0[3]);
      o[4] = (short)f2bf(v1[0]);
      o[5] = (short)f2bf(v1[1]);
      o[6] = (short)f2bf(v1[2]);
      o[7] = (short)f2bf(v1[3]);
      *(short8*)(sxb + ((s ^ r7) << 4)) = o;
    }
  }
  __syncthreads();

  f32x16 oacc[4];   // [d-tile]; C: col d = w*128 + d0*32 + c31, row tok(q,l5)
#pragma unroll
  for (int d0 = 0; d0 < 4; d0++) oacc[d0] = (f32x16)0.0f;
  f32x16 sacc;      // S chunk: col tok = c31, row m_local of wave's 32-m slice
  float fsum = 0.f;

  char* const bx0 = (char*)sX + (c31 << 10);
  char* const bp0 = (char*)sPa + (c31 << 8);

  // GEMM1 for chunk ch (m-tile MT = ch*4+w): S = memTbF_tile * X
  auto gemm1 = [&](int ch) {
    sacc = (f32x16)0.0f;
    const short8* ga = (const short8*)memTbF + (size_t)((ch * 4 + w) * 32) * 64 + lane;
#pragma unroll
    for (int kk = 0; kk < 32; kk++) {
      short8 a = ga[kk * 64];
      int sw = (((kk << 1) | l5) ^ e7) << 4;
      short8 x0 = *(const short8*)(bx0 + sw);
      sacc = MFMA32(a, x0, sacc);
    }
  };

  // P = exp(S) -> bf16 -> swizzled sPa (rows=tok, 256B; slot' = slot ^ (tok&15))
  auto pgen = [&]() {
    int tok = c31;
    char* base = (char*)sPa + (tok << 8);
    float s = 0.f;
    unsigned short pb[16];
#pragma unroll
    for (int q = 0; q < 16; q++) {
      float p = __expf(sacc[q]);
      unsigned short b = f2bf(p);
      pb[q] = b;
      s += bf2f(b);  // sum the rounded values GEMM2 will use
    }
    fsum += s;
#pragma unroll
    for (int q = 0; q < 4; q++) {
      short4v o = {(short)pb[q * 4], (short)pb[q * 4 + 1],
                   (short)pb[q * 4 + 2], (short)pb[q * 4 + 3]};
      int sl = ((w << 2) | q) ^ t15;
      *(short4v*)(base + (sl << 4) + (l5 << 3)) = o;
    }
  };

  gemm1(0);
  pgen();

#pragma unroll 1
  for (int c = 0; c < 8; c++) {
    __syncthreads();  // bar A: sPa(c) ready
    if (c == 7 && tid < BT) {
      float s = psums[tid] + psums[32 + tid] + psums[64 + tid] + psums[96 + tid];
      sInv[tid] = 1.0f / s;
    }
    // ---- region: GEMM2(c) interleaved with GEMM1(c+1) ----
    {
      const short8* gb = (const short8*)memDF + ((size_t)(w * 4) * 64 + c * 8) * 64 + lane;
      const bool doG1 = (c < 7);
      const short8* ga = (const short8*)memTbF +
                         (size_t)((((c + 1) & 7) * 4 + w) * 32) * 64 + lane;
      if (doG1) sacc = (f32x16)0.0f;
#pragma unroll
      for (int k0 = 0; k0 < 8; k0++) {
        int sp = ((((k0 << 1) | l5) ^ t15) << 4);
        short8 p0 = *(const short8*)(bp0 + sp);
        short8 b0 = gb[(0 * 64 + k0) * 64];
        short8 b1 = gb[(1 * 64 + k0) * 64];
        short8 b2 = gb[(2 * 64 + k0) * 64];
        short8 b3 = gb[(3 * 64 + k0) * 64];
        oacc[0] = MFMA32(p0, b0, oacc[0]);
        oacc[1] = MFMA32(p0, b1, oacc[1]);
        oacc[2] = MFMA32(p0, b2, oacc[2]);
        oacc[3] = MFMA32(p0, b3, oacc[3]);
        if (doG1) {
#pragma unroll
          for (int kq = 0; kq < 4; kq++) {
            int kk = k0 * 4 + kq;
            short8 a = ga[kk * 64];
            int sw = (((kk << 1) | l5) ^ e7) << 4;
            short8 x0 = *(const short8*)(bx0 + sw);
            sacc = MFMA32(a, x0, sacc);
          }
        }
      }
    }
    __syncthreads();  // bar B: sPa(c) consumed by all waves
    if (c < 7) {
      pgen();
      if (c == 6) {  // fsum now complete; publish per-wave partials (into dead sX)
        float s0 = fsum + __shfl_xor(fsum, 32);
        if (lane < 32) psums[w * 32 + lane] = s0;
      }
    }
  }

  // ---- Epilogue: O * (1/sum) ----
#pragma unroll
  for (int q = 0; q < 16; q++) {
    int tok = (q & 3) + ((q >> 2) << 3) + (l5 << 2);
    float inv = sInv[tok];
    float* op = out + (t0 + tok) * (long)D_ + w * 128 + c31;
#pragma unroll
    for (int d0 = 0; d0 < 4; d0++) op[d0 * 32] = oacc[d0][q] * inv;
  }
}

extern "C" void kernel_launch(void* const* d_in, const int* in_sizes, int n_in,
                              void* d_out, int out_size, void* d_ws, size_t ws_size,
                              hipStream_t stream) {
  const float* x = (const float*)d_in[0];
  const float* mem = (const float*)d_in[1];
  float* out = (float*)d_out;
  unsigned short* memTbF = (unsigned short*)d_ws;    // 1 MB frag-layout (scaled)
  unsigned short* memDF = memTbF + (size_t)D_ * M_;  // 1 MB frag-layout

  hipLaunchKernelGGL(prep_mem_kernel, dim3((D_ * M_) / 256), dim3(256), 0, stream,
                     mem, memTbF, memDF);
  hipLaunchKernelGGL(fused_kernel, dim3((B_ * N_) / BT), dim3(256), 0, stream,
                     x, memTbF, memDF, out);
}

// Round 12
// 507.592 us; speedup vs baseline: 1.5341x; 1.0724x over previous
//
#include <hip/hip_runtime.h>

#define B_ 16
#define N_ 8192
#define D_ 512
#define M_ 1024
#define BT 64
#define SCALE 0.04419417382415922f  // 1/sqrt(512)

typedef __attribute__((ext_vector_type(8))) short short8;
typedef __attribute__((ext_vector_type(4))) float f32x4;
typedef __attribute__((ext_vector_type(16))) float f32x16;

__device__ __forceinline__ unsigned short f2bf(float f) {
  unsigned int u = __float_as_uint(f);
  u += 0x7FFFu + ((u >> 16) & 1u);  // RNE
  return (unsigned short)(u >> 16);
}
__device__ __forceinline__ float bf2f(unsigned short h) {
  return __uint_as_float(((unsigned int)h) << 16);
}

#define MFMA32(a, b, c) __builtin_amdgcn_mfma_f32_32x32x16_bf16((a), (b), (c), 0, 0, 0)

// memTbF: GEMM1 A-frags (scaled mem, rows=m), block (MT 0..31, kk 0..31):
//   elem[l][j] = SCALE*mem[kk*16 + (l>>5)*8 + j][MT*32 + (l&31)]
// memDF: GEMM2 B-frags (mem, cols=d), block (DT 0..15, kg 0..63), with the
//   softmax-permutation pi on k matching kernel A's natural P write order:
//   storage k = kg*16 + hi*8 + j  ->  logical m = (kg>>1)*32 + 16*(kg&1)
//                                        + 4*hi + (j&3) + 8*(j>>2)
__global__ void prep_mem_kernel(const float* __restrict__ mem,
                                unsigned short* __restrict__ memTbF,
                                unsigned short* __restrict__ memDF) {
  int t = blockIdx.x * 256 + threadIdx.x;  // 0 .. D*M-1
  int j = t & 7, l = (t >> 3) & 63, blk = t >> 9;
  {
    int kk = blk & 31, MT = blk >> 5;
    int m = MT * 32 + (l & 31);
    int d = kk * 16 + ((l >> 5) << 3) + j;
    memTbF[t] = f2bf(mem[d * M_ + m] * SCALE);
  }
  {
    int kg = blk & 63, DT = blk >> 6;
    int d = DT * 32 + (l & 31);
    int hi = l >> 5;
    int m = (kg >> 1) * 32 + ((kg & 1) << 4) + (hi << 2) + (j & 3) + ((j >> 2) << 3);
    memDF[t] = f2bf(mem[d * M_ + m]);
  }
}

// Kernel A: P = exp(x*mem/sqrt(D)) -> bf16 frag-blocks in Pf (= d_out), plus
// per-token denominator reciprocals. Barrier-free main loop.
__global__ __launch_bounds__(256, 2) void gemm1_exp_kernel(
    const float* __restrict__ x, const unsigned short* __restrict__ memTbF,
    unsigned short* __restrict__ Pf, float* __restrict__ denomInv) {
  __shared__ unsigned short sX[32768];  // 64 KB: X bf16, 64 rows x 1024B, XOR-swizzled
  __shared__ float psums[4][64];

  const int tid = threadIdx.x;
  const int w = tid >> 6;     // wave 0..3
  const int lane = tid & 63;
  const int c31 = lane & 31;
  const int l5 = lane >> 5;
  const int e7 = lane & 7;
  const long t0 = (long)blockIdx.x * BT;

  // ---- Stage X -> bf16 -> swizzled sX (slot' = slot ^ (row&7), 16B slots) ----
  {
    const int row = tid >> 2, cg = tid & 3;
    const int r7 = row & 7;
    const float* xp = x + (t0 + row) * (long)D_ + cg * 128;
    char* sxb = (char*)sX + (row << 10);
#pragma unroll
    for (int j = 0; j < 16; j++) {
      f32x4 v0 = *(const f32x4*)(xp + j * 8);
      f32x4 v1 = *(const f32x4*)(xp + j * 8 + 4);
      short8 o;
      o[0] = (short)f2bf(v0[0]);
      o[1] = (short)f2bf(v0[1]);
      o[2] = (short)f2bf(v0[2]);
      o[3] = (short)f2bf(v0[3]);
      o[4] = (short)f2bf(v1[0]);
      o[5] = (short)f2bf(v1[1]);
      o[6] = (short)f2bf(v1[2]);
      o[7] = (short)f2bf(v1[3]);
      int s = (cg << 4) + j;
      *(short8*)(sxb + ((s ^ r7) << 4)) = o;
    }
  }
  __syncthreads();

  char* const bx0 = (char*)sX + (c31 << 10);
  char* const bx1 = (char*)sX + ((32 + c31) << 10);
  short8* const Pf8 = (short8*)Pf;
  float fsum0 = 0.f, fsum1 = 0.f;

  // exp + pack + store one S-tile (value param -> static codegen per callsite)
  auto emit = [&](f32x16 sv, int tt, int mtile) {
    unsigned short pb[16];
    float s = 0.f;
#pragma unroll
    for (int q = 0; q < 16; q++) {
      float p = __expf(sv[q]);
      unsigned short b = f2bf(p);
      pb[q] = b;
      s += bf2f(b);  // sum the rounded values GEMM2 will use
    }
    if (tt == 0) fsum0 += s; else fsum1 += s;
    size_t TTg = (size_t)blockIdx.x * 2 + tt;
#pragma unroll
    for (int sb = 0; sb < 2; sb++) {
      short8 o;
#pragma unroll
      for (int e = 0; e < 8; e++) o[e] = (short)pb[sb * 8 + e];
      Pf8[(TTg * 64 + (size_t)(mtile * 2 + sb)) * 64 + lane] = o;
    }
  };

#pragma unroll 1
  for (int i = 0; i < 4; i++) {
    const int mt0 = i * 8 + w * 2;  // this wave's m-tile pair
    f32x16 s00 = (f32x16)0.0f, s01 = (f32x16)0.0f;
    f32x16 s10 = (f32x16)0.0f, s11 = (f32x16)0.0f;
    const short8* ga0 = (const short8*)memTbF + (size_t)(mt0 * 32) * 64 + lane;
    const short8* ga1 = ga0 + 32 * 64;
#pragma unroll 8
    for (int kk = 0; kk < 32; kk++) {
      short8 a0 = ga0[kk * 64];
      short8 a1 = ga1[kk * 64];
      int sw = (((kk << 1) | l5) ^ e7) << 4;
      short8 x0 = *(const short8*)(bx0 + sw);
      short8 x1 = *(const short8*)(bx1 + sw);
      s00 = MFMA32(a0, x0, s00);
      s01 = MFMA32(a0, x1, s01);
      s10 = MFMA32(a1, x0, s10);
      s11 = MFMA32(a1, x1, s11);
    }
    emit(s00, 0, mt0);
    emit(s01, 1, mt0);
    emit(s10, 0, mt0 + 1);
    emit(s11, 1, mt0 + 1);
  }

  // ---- Denominator reduce (2 barriers total in kernel) ----
  fsum0 += __shfl_xor(fsum0, 32);
  fsum1 += __shfl_xor(fsum1, 32);
  if (l5 == 0) {
    psums[w][c31] = fsum0;
    psums[w][32 + c31] = fsum1;
  }
  __syncthreads();
  if (tid < 64)
    denomInv[t0 + tid] =
        1.0f / (psums[0][tid] + psums[1][tid] + psums[2][tid] + psums[3][tid]);
}

// Kernel B: out = (P * mem) * (1/denom). Pure barrier-free GEMM; P-frags
// stream from HBM (each block read once), memDF from L2. Each WG's out
// window is exactly its own P window (RAW legalized by the one barrier).
__global__ __launch_bounds__(256, 2) void gemm2_kernel(
    const unsigned short* __restrict__ Pf, const unsigned short* __restrict__ memDF,
    const float* __restrict__ denomInv, float* __restrict__ out) {
  __shared__ float sInv[64];
  const int tid = threadIdx.x;
  const int w = tid >> 6;     // wave 0..3 -> d-slice w*128
  const int lane = tid & 63;
  const int c31 = lane & 31;
  const int l5 = lane >> 5;
  const long t0 = (long)blockIdx.x * BT;
  if (tid < 64) sInv[tid] = denomInv[t0 + tid];

  f32x16 oacc[2][4];
#pragma unroll
  for (int tt = 0; tt < 2; tt++)
#pragma unroll
    for (int d0 = 0; d0 < 4; d0++) oacc[tt][d0] = (f32x16)0.0f;

  const short8* pa0 = (const short8*)Pf + ((size_t)blockIdx.x * 2) * 4096 + lane;
  const short8* pa1 = pa0 + 4096;
  const short8* gb = (const short8*)memDF + (size_t)(w * 4) * 4096 + lane;

#pragma unroll 4
  for (int kg = 0; kg < 64; kg++) {
    short8 p0 = pa0[kg * 64];
    short8 p1 = pa1[kg * 64];
    short8 b0 = gb[(0 * 64 + kg) * 64];
    short8 b1 = gb[(1 * 64 + kg) * 64];
    short8 b2 = gb[(2 * 64 + kg) * 64];
    short8 b3 = gb[(3 * 64 + kg) * 64];
    oacc[0][0] = MFMA32(p0, b0, oacc[0][0]);
    oacc[1][0] = MFMA32(p1, b0, oacc[1][0]);
    oacc[0][1] = MFMA32(p0, b1, oacc[0][1]);
    oacc[1][1] = MFMA32(p1, b1, oacc[1][1]);
    oacc[0][2] = MFMA32(p0, b2, oacc[0][2]);
    oacc[1][2] = MFMA32(p1, b2, oacc[1][2]);
    oacc[0][3] = MFMA32(p0, b3, oacc[0][3]);
    oacc[1][3] = MFMA32(p1, b3, oacc[1][3]);
  }

  __syncthreads();  // all P reads complete (vmcnt drain) + sInv staged

  // ---- Epilogue: overwrite this WG's P window with out = O * (1/sum) ----
#pragma unroll
  for (int tt = 0; tt < 2; tt++) {
#pragma unroll
    for (int q = 0; q < 16; q++) {
      int tok = tt * 32 + (q & 3) + ((q >> 2) << 3) + (l5 << 2);
      float inv = sInv[tok];
      float* op = out + (t0 + tok) * (long)D_ + w * 128 + c31;
#pragma unroll
      for (int d0 = 0; d0 < 4; d0++) op[d0 * 32] = oacc[tt][d0][q] * inv;
    }
  }
}

extern "C" void kernel_launch(void* const* d_in, const int* in_sizes, int n_in,
                              void* d_out, int out_size, void* d_ws, size_t ws_size,
                              hipStream_t stream) {
  const float* x = (const float*)d_in[0];
  const float* mem = (const float*)d_in[1];
  float* out = (float*)d_out;
  unsigned short* memTbF = (unsigned short*)d_ws;    // 1 MB frag-layout (scaled)
  unsigned short* memDF = memTbF + (size_t)D_ * M_;  // 1 MB frag-layout (pi-permuted k)
  float* denomInv = (float*)(memDF + (size_t)D_ * M_);  // 512 KB
  unsigned short* Pf = (unsigned short*)d_out;       // P bf16 == d_out byte-size

  hipLaunchKernelGGL(prep_mem_kernel, dim3((D_ * M_) / 256), dim3(256), 0, stream,
                     mem, memTbF, memDF);
  hipLaunchKernelGGL(gemm1_exp_kernel, dim3((B_ * N_) / BT), dim3(256), 0, stream,
                     x, memTbF, Pf, denomInv);
  hipLaunchKernelGGL(gemm2_kernel, dim3((B_ * N_) / BT), dim3(256), 0, stream,
                     Pf, memDF, denomInv, out);
}